// Round 7
// baseline (177.395 us; speedup 1.0000x reference)
//
#include <hip/hip_runtime.h>

#define BATCH   131072
#define IN_DIM  256
#define OUT_DIM 32
#define N_INNER 255
#define N_LEAF  256
#define OUT_HDR (BATCH * OUT_DIM)

#define TILE_M  128
#define BK      32
#define NTHR    512
#define NCHUNK  8
#define PSTR    272                      // u16; 544B row stride = 32 mod 128 -> disjoint bank windows
#define INV64K  (1.0f / 65536.0f)
#define PROW_PAD 1040                    // f32 p-row stride in LDS (1024 + 16 pad)

// ---- d_ws layout (bytes) ----
#define WS_QT_HI   0                     // [32 cols][256 leaves] bf16
#define WS_QT_LO   16384
#define WS_WIMG_HI 32768                 // [8 chunk][4 kg][256 node][16B] bf16-hi
#define WS_WIMG_LO (32768 + 131072)      // same layout, bf16-lo

// ---- LDS layout (bytes) ----
// WBUF  [0, 32768)      W single buffer: hi 16K ([kg][node][16B]) + lo 16K
// XB0   [32768, 49408)  x buf 0: hi 4x2080 + lo 4x2080 (padded segs)
// XB1   [49408, 66048)  x buf 1
// tail overlays: prob u16 [128][PSTR] at 0 (69632B);
//                p f32 half [64][PROW_PAD] at 0 (66544B, twice);
//                P bf16 image [kc8][koct4][row128][16B]+skew at 0 (two passes)
#define WBUF 0
#define XSEG 2080
#define XHALF 8320                       // 4*XSEG
#define XB0   32768
#define XB1   49408
#define SMEM_BYTES 69632                 // -> 2 blocks/CU

typedef __attribute__((ext_vector_type(8))) short bf16x8;
typedef __attribute__((ext_vector_type(4))) float f32x4;

__device__ __forceinline__ unsigned short bf16rne(float a) {
    unsigned u = __float_as_uint(a);
    return (unsigned short)((u + 0x7FFFu + ((u >> 16) & 1u)) >> 16);
}
// packed f32x2 -> bf16x2 RNE in one instruction (dst[15:0]=bf16(a), dst[31:16]=bf16(b))
__device__ __forceinline__ unsigned cvtpk(float a, float b) {
    unsigned r;
    asm("v_cvt_pk_bf16_f32 %0, %1, %2" : "=v"(r) : "v"(a), "v"(b));
    return r;
}
__device__ __forceinline__ unsigned packhi2(float a, float b) { return cvtpk(a, b); }
__device__ __forceinline__ unsigned packlo2(float a, float b) {
    unsigned h = cvtpk(a, b);
    float ra = a - __uint_as_float(h << 16);
    float rb = b - __uint_as_float(h & 0xFFFF0000u);
    return cvtpk(ra, rb);
}
__device__ __forceinline__ void split2(float a, float b, unsigned& hi, unsigned& lo) {
    unsigned short ha = bf16rne(a), hb = bf16rne(b);
    hi = (unsigned)ha | ((unsigned)hb << 16);
    float ra = a - __uint_as_float((unsigned)ha << 16);
    float rb = b - __uint_as_float((unsigned)hb << 16);
    lo = (unsigned)bf16rne(ra) | ((unsigned)bf16rne(rb) << 16);
}
// cheap trunc split (numerically verified rounds 1-6)
__device__ __forceinline__ void tsplit2(float a, float b, unsigned& h, unsigned& l) {
    unsigned ua = __float_as_uint(a), ub = __float_as_uint(b);
    h = (ua >> 16) | (ub & 0xFFFF0000u);
    float ra = a - __uint_as_float(ua & 0xFFFF0000u);
    float rb = b - __uint_as_float(ub & 0xFFFF0000u);
    l = (__float_as_uint(ra) >> 16) | (__float_as_uint(rb) & 0xFFFF0000u);
}

__device__ __forceinline__ void gload16(const void* g, void* l) {
    __builtin_amdgcn_global_load_lds(
        (const __attribute__((address_space(1))) unsigned int*)g,
        (__attribute__((address_space(3))) unsigned int*)l, 16, 0, 0);
}

// ---------------- setup: W -> hi/lo bf16 chunk images ----------------
__global__ void wsplit_k(const float* __restrict__ W,
                         unsigned int* __restrict__ whi, unsigned int* __restrict__ wlo) {
    int gid = blockIdx.x * 512 + threadIdx.x;      // 0..8191
    int n   = gid >> 5;                            // node 0..255
    int oct = gid & 31;                            // k-octet
    float4 a = make_float4(0.f,0.f,0.f,0.f), b = a;
    if (n < N_INNER) {
        a = *(const float4*)(W + (size_t)n * IN_DIM + oct * 8);
        b = *(const float4*)(W + (size_t)n * IN_DIM + oct * 8 + 4);
    }
    uint4 h, l;
    split2(a.x, a.y, h.x, l.x); split2(a.z, a.w, h.y, l.y);
    split2(b.x, b.y, h.z, l.z); split2(b.z, b.w, h.w, l.w);
    int c = oct >> 2, kg = oct & 3;
    size_t off = ((size_t)(c * 4 + kg) * 256 + n) * 4;   // uints
    *(uint4*)(whi + off) = h;
    *(uint4*)(wlo + off) = l;
}

// ---------------- setup: Q = softmax(leaf), transposed hi/lo bf16 ----------------
__global__ void qt_k(const float* __restrict__ leaf,
                     unsigned short* __restrict__ qhi, unsigned short* __restrict__ qlo) {
    int l = threadIdx.x;                           // leaf 0..255
    const float* row = leaf + l * OUT_DIM;
    float v[OUT_DIM];
    float mx = -1e30f;
#pragma unroll
    for (int o = 0; o < OUT_DIM; ++o) { v[o] = row[o]; mx = fmaxf(mx, v[o]); }
    float s = 0.f;
#pragma unroll
    for (int o = 0; o < OUT_DIM; ++o) { v[o] = __expf(v[o] - mx); s += v[o]; }
    float r = 1.f / s;
#pragma unroll
    for (int o = 0; o < OUT_DIM; ++o) {
        float q = v[o] * r;
        unsigned short h = bf16rne(q);
        float res = q - __uint_as_float((unsigned)h << 16);
        qhi[o * 256 + l] = h;
        qlo[o * 256 + l] = bf16rne(res);
    }
}

// tree DP stage, qq = top-2 leaf bits (4 threads/row, 64 leaves each)
#define TREE_STAGE(D) { \
    const int base_ = (1 << (D)) - 1 + (qq << ((D) - 2)); \
    _Pragma("unroll") \
    for (int i = (1 << ((D) - 2)) - 1; i >= 0; --i) { \
        float pr_ = (float)pb[base_ + i] * INV64K; \
        float a_  = P[i]; \
        float lv_ = a_ * pr_; \
        P[2*i]     = lv_; \
        P[2*i + 1] = a_ - lv_; \
    } }

#define MFMA_BF16(A, B, C) __builtin_amdgcn_mfma_f32_16x16x32_bf16(A, B, C, 0, 0, 0)

// ---------------- fused main kernel ----------------
// R6 main loop (TILE_M=128, W single-buffer 2-barrier cadence, x dbuf).
// NEW tail: p routed through LDS in two 64-row halves and stored to global
// fully coalesced (fixes ~2x HBM write amplification of scattered stores);
// P images packed with v_cvt_pk_bf16_f32.
__launch_bounds__(NTHR, 4)
__global__ void tree_k(const float* __restrict__ x,
                       const float* __restrict__ bv, const float* __restrict__ beta,
                       const unsigned short* __restrict__ qhi, const unsigned short* __restrict__ qlo,
                       const char* __restrict__ wimg_hi, const char* __restrict__ wimg_lo,
                       float* __restrict__ out) {
    extern __shared__ char smem[];
    const int tid  = threadIdx.x;
    const int row0 = blockIdx.x * TILE_M;

    const int lane  = tid & 63;
    const int w     = tid >> 6;          // wave 0..7
    const int col16 = lane & 15;
    const int hi4   = lane >> 4;         // k-octet 0..3
    const int wr    = w >> 2;            // row half (0..1)
    const int wc    = w & 3;             // col group (0..3)

    f32x4 acc[4][4];
#pragma unroll
    for (int i = 0; i < 4; ++i)
#pragma unroll
        for (int j = 0; j < 4; ++j) acc[i][j] = (f32x4){0.f, 0.f, 0.f, 0.f};

    const int xrow = tid >> 2;           // 0..127
    const int xk   = tid & 3;            // k-octet staged by this thread
    const int xwoff = xk * XSEG + xrow * 16;
    const float* xsrc = x + (size_t)(row0 + xrow) * IN_DIM + xk * 8;

    // ---- prologue: stage W(0) + x(0) ----
    {
        char* dh = smem + WBUF + w * 1024;
        char* dl = dh + 16384;
        gload16(wimg_hi + tid * 16,        dh);
        gload16(wimg_hi + 8192 + tid * 16, dh + 8192);
        gload16(wimg_lo + tid * 16,        dl);
        gload16(wimg_lo + 8192 + tid * 16, dl + 8192);
        float4 a = *(const float4*)(xsrc);
        float4 b = *(const float4*)(xsrc + 4);
        uint4 h, l;
        tsplit2(a.x, a.y, h.x, l.x); tsplit2(a.z, a.w, h.y, l.y);
        tsplit2(b.x, b.y, h.z, l.z); tsplit2(b.z, b.w, h.w, l.w);
        *(uint4*)(smem + XB0 + xwoff)         = h;
        *(uint4*)(smem + XB0 + XHALF + xwoff) = l;
    }
    asm volatile("s_waitcnt vmcnt(0) lgkmcnt(0)" ::: "memory");
    __builtin_amdgcn_sched_barrier(0);
    __builtin_amdgcn_s_barrier();
    __builtin_amdgcn_sched_barrier(0);

#pragma unroll 1
    for (int c = 0; c < NCHUNK; ++c) {
        const char* xb  = smem + ((c & 1) ? XB1 : XB0);
        char*       xbn = smem + ((c & 1) ? XB0 : XB1);
        const bool more = (c + 1 < NCHUNK);

        // ---- A-frags: 4 rf x (hi,lo) from padded x LDS ----
        bf16x8 ah[4], al[4];
#pragma unroll
        for (int rf = 0; rf < 4; ++rf) {
            int ao = hi4 * XSEG + (wr * 64 + rf * 16 + col16) * 16;
            ah[rf] = *(const bf16x8*)(xb + ao);
            al[rf] = *(const bf16x8*)(xb + XHALF + ao);
        }
        // ---- MFMA: cf-outer, 12 per cf ----
#pragma unroll
        for (int cf = 0; cf < 4; ++cf) {
            int bo = hi4 * 4096 + (wc * 64 + cf * 16 + col16) * 16;
            bf16x8 bh = *(const bf16x8*)(smem + WBUF + bo);
            bf16x8 bl = *(const bf16x8*)(smem + WBUF + 16384 + bo);
#pragma unroll
            for (int rf = 0; rf < 4; ++rf) {
                acc[rf][cf] = MFMA_BF16(ah[rf], bh, acc[rf][cf]);
                acc[rf][cf] = MFMA_BF16(al[rf], bh, acc[rf][cf]);
                acc[rf][cf] = MFMA_BF16(ah[rf], bl, acc[rf][cf]);
            }
        }

        // ---- stage x(c+1) into the other buffer ----
        if (more) {
            float4 a = *(const float4*)(xsrc + (c + 1) * BK);
            float4 b = *(const float4*)(xsrc + (c + 1) * BK + 4);
            uint4 h, l;
            tsplit2(a.x, a.y, h.x, l.x); tsplit2(a.z, a.w, h.y, l.y);
            tsplit2(b.x, b.y, h.z, l.z); tsplit2(b.z, b.w, h.w, l.w);
            *(uint4*)(xbn + xwoff)         = h;
            *(uint4*)(xbn + XHALF + xwoff) = l;
        }
        // bar A: all W(c)/x(c) reads consumed + my x writes visible
        asm volatile("s_waitcnt lgkmcnt(0)" ::: "memory");
        __builtin_amdgcn_sched_barrier(0);
        __builtin_amdgcn_s_barrier();
        __builtin_amdgcn_sched_barrier(0);

        if (more) {
            // ---- stage W(c+1) into the (now fully-read) single buffer ----
            const char* gh = wimg_hi + (size_t)(c + 1) * 16384;
            const char* gl = wimg_lo + (size_t)(c + 1) * 16384;
            char* dh = smem + WBUF + w * 1024;
            char* dl = dh + 16384;
            gload16(gh + tid * 16,        dh);
            gload16(gh + 8192 + tid * 16, dh + 8192);
            gload16(gl + tid * 16,        dl);
            gload16(gl + 8192 + tid * 16, dl + 8192);
            // bar B: W(c+1) DMA complete
            asm volatile("s_waitcnt vmcnt(0)" ::: "memory");
            __builtin_amdgcn_sched_barrier(0);
            __builtin_amdgcn_s_barrier();
            __builtin_amdgcn_sched_barrier(0);
        }
    }

    // ---- epilogue: prob = sigmoid(beta*(logit+b)) -> u16 LDS [128][PSTR] ----
    unsigned short* prob = (unsigned short*)smem;
    {
        float bb[4], bt[4];
#pragma unroll
        for (int cf = 0; cf < 4; ++cf) {
            int col = wc * 64 + cf * 16 + col16;
            bb[cf] = (col < N_INNER) ? bv[col]   : 0.f;
            bt[cf] = (col < N_INNER) ? beta[col] : 0.f;
        }
#pragma unroll
        for (int rf = 0; rf < 4; ++rf)
#pragma unroll
            for (int cf = 0; cf < 4; ++cf) {
                int col = wc * 64 + cf * 16 + col16;
#pragma unroll
                for (int r = 0; r < 4; ++r) {
                    int row = wr * 64 + rf * 16 + hi4 * 4 + r;
                    float t = (acc[rf][cf][r] + bb[cf]) * bt[cf];
                    float s = 1.f / (1.f + __expf(-t));
                    float u = fminf(s * 65536.f + 0.5f, 65535.f);
                    prob[row * PSTR + col] = (unsigned short)(unsigned)u;
                }
            }
    }
    __syncthreads();                 // B0: prob visible

    // ---- tree expansion: 4 threads/row, 64 leaves each ----
    const int prow = tid >> 2;           // 0..127
    const int qq   = tid & 3;            // top-2 leaf bits
    const unsigned short* pb = prob + prow * PSTR;
    float P[64];
    {
        float p0 = (float)pb[0] * INV64K;             float f0 = (qq & 2) ? (1.f - p0) : p0;
        float p1 = (float)pb[1 + (qq >> 1)] * INV64K; float f1 = (qq & 1) ? (1.f - p1) : p1;
        P[0] = f0 * f1;
    }
    TREE_STAGE(2) TREE_STAGE(3) TREE_STAGE(4) TREE_STAGE(5) TREE_STAGE(6) TREE_STAGE(7)

    __syncthreads();                 // B1: all prob reads done (LDS reusable)

    // ---- p -> global, COALESCED via LDS routing (two 64-row halves) ----
#pragma unroll 1
    for (int h = 0; h < 2; ++h) {
        if ((prow >> 6) == h) {
            char* base = smem + (prow & 63) * PROW_PAD + qq * 256;
#pragma unroll
            for (int m = 0; m < 16; ++m)
                *(float4*)(base + m * 16) = make_float4(P[4*m], P[4*m+1], P[4*m+2], P[4*m+3]);
        }
        __syncthreads();             // half-h p data visible
        {
            char* dstc = (char*)(out + OUT_HDR) + (((size_t)row0 + h * 64) << 10);
#pragma unroll
            for (int i = 0; i < 8; ++i) {
                int L = tid * 16 + i * 8192;          // 0..65520, contiguous per wave
                int r = L >> 10, off = L & 1023;
                uint4 v = *(const uint4*)(smem + r * PROW_PAD + off);
                *(uint4*)(dstc + L) = v;
            }
        }
        __syncthreads();             // LDS reads done -> region reusable
    }

    // ---- P hi-image overlaying: [kc 8][koct 4][row 128][16B] + qq*32 skew ----
#pragma unroll
    for (int kk = 0; kk < 2; ++kk)
#pragma unroll
        for (int g = 0; g < 4; ++g) {
            int b = kk * 32 + g * 8;
            uint4 hh;
            hh.x = packhi2(P[b+0], P[b+1]);
            hh.y = packhi2(P[b+2], P[b+3]);
            hh.z = packhi2(P[b+4], P[b+5]);
            hh.w = packhi2(P[b+6], P[b+7]);
            *(uint4*)(smem + (2*qq + kk) * 8192 + g * 2048 + prow * 16 + qq * 32) = hh;
        }
    __syncthreads();                 // B2: hi image visible

    // ---- out = p @ Q via MFMA; wave w owns rows w*16..w*16+15, cols 0..31 ----
    f32x4 acc2[2];
    acc2[0] = (f32x4){0.f,0.f,0.f,0.f};
    acc2[1] = (f32x4){0.f,0.f,0.f,0.f};
    const int arow = w * 16 + col16;

    // pass A: P_hi x (Q_hi + Q_lo)
#pragma unroll
    for (int kc = 0; kc < 8; ++kc) {
        bf16x8 pa = *(const bf16x8*)(smem + kc * 8192 + hi4 * 2048 + arow * 16 + (kc >> 1) * 32);
#pragma unroll
        for (int cf = 0; cf < 2; ++cf) {
            int qo = (cf * 16 + col16) * 256 + kc * 32 + hi4 * 8;
            bf16x8 qbh = *(const bf16x8*)(qhi + qo);
            bf16x8 qbl = *(const bf16x8*)(qlo + qo);
            acc2[cf] = MFMA_BF16(pa, qbh, acc2[cf]);
            acc2[cf] = MFMA_BF16(pa, qbl, acc2[cf]);
        }
    }
    __syncthreads();                 // B3: P_hi reads done

    // ---- P lo-image overwrite ----
#pragma unroll
    for (int kk = 0; kk < 2; ++kk)
#pragma unroll
        for (int g = 0; g < 4; ++g) {
            int b = kk * 32 + g * 8;
            uint4 ll;
            ll.x = packlo2(P[b+0], P[b+1]);
            ll.y = packlo2(P[b+2], P[b+3]);
            ll.z = packlo2(P[b+4], P[b+5]);
            ll.w = packlo2(P[b+6], P[b+7]);
            *(uint4*)(smem + (2*qq + kk) * 8192 + g * 2048 + prow * 16 + qq * 32) = ll;
        }
    __syncthreads();                 // B4

    // pass B: P_lo x Q_hi, then store out
#pragma unroll
    for (int kc = 0; kc < 8; ++kc) {
        bf16x8 pl = *(const bf16x8*)(smem + kc * 8192 + hi4 * 2048 + arow * 16 + (kc >> 1) * 32);
#pragma unroll
        for (int cf = 0; cf < 2; ++cf) {
            int qo = (cf * 16 + col16) * 256 + kc * 32 + hi4 * 8;
            bf16x8 qbh = *(const bf16x8*)(qhi + qo);
            acc2[cf] = MFMA_BF16(pl, qbh, acc2[cf]);
        }
    }
#pragma unroll
    for (int cf = 0; cf < 2; ++cf)
#pragma unroll
        for (int r = 0; r < 4; ++r) {
            int row = w * 16 + hi4 * 4 + r;
            out[(size_t)(row0 + row) * OUT_DIM + cf * 16 + col16] = acc2[cf][r];
        }
}

extern "C" void kernel_launch(void* const* d_in, const int* in_sizes, int n_in,
                              void* d_out, int out_size, void* d_ws, size_t ws_size,
                              hipStream_t stream) {
    const float* x    = (const float*)d_in[0];
    const float* W    = (const float*)d_in[1];
    const float* bv   = (const float*)d_in[2];
    const float* beta = (const float*)d_in[3];
    const float* leaf = (const float*)d_in[4];
    float* out = (float*)d_out;
    char* ws = (char*)d_ws;

    unsigned short* qhi = (unsigned short*)(ws + WS_QT_HI);
    unsigned short* qlo = (unsigned short*)(ws + WS_QT_LO);
    char* whi = ws + WS_WIMG_HI;
    char* wlo = ws + WS_WIMG_LO;

    hipFuncSetAttribute(reinterpret_cast<const void*>(tree_k),
                        hipFuncAttributeMaxDynamicSharedMemorySize, SMEM_BYTES);

    wsplit_k<<<16, 512, 0, stream>>>(W, (unsigned int*)whi, (unsigned int*)wlo);
    qt_k<<<1, 256, 0, stream>>>(leaf, qhi, qlo);
    tree_k<<<BATCH / TILE_M, NTHR, SMEM_BYTES, stream>>>(
        x, bv, beta, qhi, qlo, whi, wlo, out);
}

// Round 9
// 148.240 us; speedup vs baseline: 1.1967x; 1.1967x over previous
//
#include <hip/hip_runtime.h>

#define BATCH   131072
#define IN_DIM  256
#define OUT_DIM 32
#define N_INNER 255
#define N_LEAF  256
#define OUT_HDR (BATCH * OUT_DIM)

#define TILE_M  128
#define BK      32
#define NTHR    512
#define NCHUNK  8
#define PSTR    272                      // u16; 544B row stride = 32 mod 128 -> disjoint bank windows
#define INV64K  (1.0f / 65536.0f)

// ---- d_ws layout (bytes) ----
#define WS_QT_HI   0                     // [32 cols][256 leaves] bf16
#define WS_QT_LO   16384
#define WS_WIMG_HI 32768                 // [8 chunk][4 kg][256 node][16B] bf16-hi
#define WS_WIMG_LO (32768 + 131072)      // same layout, bf16-lo

// ---- LDS layout (bytes) ----
// WBUF  [0, 32768)      W single buffer: hi 16K ([kg][node][16B]) + lo 16K
// XB0   [32768, 49408)  x buf 0: hi 4x2080 + lo 4x2080 (padded segs)
// XB1   [49408, 66048)  x buf 1
// tail overlays: prob u16 [128][PSTR] at 0 (69632B); P image in two passes
#define WBUF 0
#define XSEG 2080
#define XHALF 8320                       // 4*XSEG
#define XBSZ  16640
#define XB0   32768
#define XB1   49408
#define SMEM_BYTES 69632                 // -> 2 blocks/CU

typedef __attribute__((ext_vector_type(8))) short bf16x8;
typedef __attribute__((ext_vector_type(4))) float f32x4;

__device__ __forceinline__ unsigned short bf16rne(float a) {
    unsigned u = __float_as_uint(a);
    return (unsigned short)((u + 0x7FFFu + ((u >> 16) & 1u)) >> 16);
}
__device__ __forceinline__ unsigned packhi2(float a, float b) {
    return (unsigned)bf16rne(a) | ((unsigned)bf16rne(b) << 16);
}
__device__ __forceinline__ unsigned packlo2(float a, float b) {
    unsigned short ha = bf16rne(a), hb = bf16rne(b);
    float ra = a - __uint_as_float((unsigned)ha << 16);
    float rb = b - __uint_as_float((unsigned)hb << 16);
    return (unsigned)bf16rne(ra) | ((unsigned)bf16rne(rb) << 16);
}
__device__ __forceinline__ void split2(float a, float b, unsigned& hi, unsigned& lo) {
    unsigned short ha = bf16rne(a), hb = bf16rne(b);
    hi = (unsigned)ha | ((unsigned)hb << 16);
    float ra = a - __uint_as_float((unsigned)ha << 16);
    float rb = b - __uint_as_float((unsigned)hb << 16);
    lo = (unsigned)bf16rne(ra) | ((unsigned)bf16rne(rb) << 16);
}
// cheap trunc split (numerically verified rounds 1-8)
__device__ __forceinline__ void tsplit2(float a, float b, unsigned& h, unsigned& l) {
    unsigned ua = __float_as_uint(a), ub = __float_as_uint(b);
    h = (ua >> 16) | (ub & 0xFFFF0000u);
    float ra = a - __uint_as_float(ua & 0xFFFF0000u);
    float rb = b - __uint_as_float(ub & 0xFFFF0000u);
    l = (__float_as_uint(ra) >> 16) | (__float_as_uint(rb) & 0xFFFF0000u);
}

__device__ __forceinline__ void gload16(const void* g, void* l) {
    __builtin_amdgcn_global_load_lds(
        (const __attribute__((address_space(1))) unsigned int*)g,
        (__attribute__((address_space(3))) unsigned int*)l, 16, 0, 0);
}

// ---------------- setup: W -> hi/lo bf16 chunk images ----------------
__global__ void wsplit_k(const float* __restrict__ W,
                         unsigned int* __restrict__ whi, unsigned int* __restrict__ wlo) {
    int gid = blockIdx.x * 512 + threadIdx.x;      // 0..8191
    int n   = gid >> 5;                            // node 0..255
    int oct = gid & 31;                            // k-octet
    float4 a = make_float4(0.f,0.f,0.f,0.f), b = a;
    if (n < N_INNER) {
        a = *(const float4*)(W + (size_t)n * IN_DIM + oct * 8);
        b = *(const float4*)(W + (size_t)n * IN_DIM + oct * 8 + 4);
    }
    uint4 h, l;
    split2(a.x, a.y, h.x, l.x); split2(a.z, a.w, h.y, l.y);
    split2(b.x, b.y, h.z, l.z); split2(b.z, b.w, h.w, l.w);
    int c = oct >> 2, kg = oct & 3;
    size_t off = ((size_t)(c * 4 + kg) * 256 + n) * 4;   // uints
    *(uint4*)(whi + off) = h;
    *(uint4*)(wlo + off) = l;
}

// ---------------- setup: Q = softmax(leaf), transposed hi/lo bf16 ----------------
__global__ void qt_k(const float* __restrict__ leaf,
                     unsigned short* __restrict__ qhi, unsigned short* __restrict__ qlo) {
    int l = threadIdx.x;                           // leaf 0..255
    const float* row = leaf + l * OUT_DIM;
    float v[OUT_DIM];
    float mx = -1e30f;
#pragma unroll
    for (int o = 0; o < OUT_DIM; ++o) { v[o] = row[o]; mx = fmaxf(mx, v[o]); }
    float s = 0.f;
#pragma unroll
    for (int o = 0; o < OUT_DIM; ++o) { v[o] = __expf(v[o] - mx); s += v[o]; }
    float r = 1.f / s;
#pragma unroll
    for (int o = 0; o < OUT_DIM; ++o) {
        float q = v[o] * r;
        unsigned short h = bf16rne(q);
        float res = q - __uint_as_float((unsigned)h << 16);
        qhi[o * 256 + l] = h;
        qlo[o * 256 + l] = bf16rne(res);
    }
}

// tree DP stage, qq = top-2 leaf bits (4 threads/row, 64 leaves each)
#define TREE_STAGE(D) { \
    const int base_ = (1 << (D)) - 1 + (qq << ((D) - 2)); \
    _Pragma("unroll") \
    for (int i = (1 << ((D) - 2)) - 1; i >= 0; --i) { \
        float pr_ = (float)pb[base_ + i] * INV64K; \
        float a_  = P[i]; \
        float lv_ = a_ * pr_; \
        P[2*i]     = lv_; \
        P[2*i + 1] = a_ - lv_; \
    } }

#define MFMA_BF16(A, B, C) __builtin_amdgcn_mfma_f32_16x16x32_bf16(A, B, C, 0, 0, 0)

// ---------------- fused main kernel ----------------
// TILE_M=128: W (hi+lo) staged ONCE per 128 rows (single 32KB buffer,
// 2-barrier cadence); x hi/lo split-staged, double-buffered, padded segs.
// Amortizes W DMA + barrier ladder + tail fixed costs 2x per row.
__launch_bounds__(NTHR, 4)
__global__ void tree_k(const float* __restrict__ x,
                       const float* __restrict__ bv, const float* __restrict__ beta,
                       const unsigned short* __restrict__ qhi, const unsigned short* __restrict__ qlo,
                       const char* __restrict__ wimg_hi, const char* __restrict__ wimg_lo,
                       float* __restrict__ out) {
    extern __shared__ char smem[];
    const int tid  = threadIdx.x;
    const int row0 = blockIdx.x * TILE_M;

    const int lane  = tid & 63;
    const int w     = tid >> 6;          // wave 0..7
    const int col16 = lane & 15;
    const int hi4   = lane >> 4;         // k-octet 0..3
    const int wr    = w >> 2;            // row half (0..1): rows wr*64 + rf*16 + col16
    const int wc    = w & 3;             // col group (0..3): cols wc*64 + cf*16 + col16

    f32x4 acc[4][4];
#pragma unroll
    for (int i = 0; i < 4; ++i)
#pragma unroll
        for (int j = 0; j < 4; ++j) acc[i][j] = (f32x4){0.f, 0.f, 0.f, 0.f};

    const int xrow = tid >> 2;           // 0..127
    const int xk   = tid & 3;            // k-octet staged by this thread
    const int xwoff = xk * XSEG + xrow * 16;
    const float* xsrc = x + (size_t)(row0 + xrow) * IN_DIM + xk * 8;

    // ---- prologue: stage W(0) + x(0) ----
    {
        char* dh = smem + WBUF + w * 1024;
        char* dl = dh + 16384;
        gload16(wimg_hi + tid * 16,        dh);
        gload16(wimg_hi + 8192 + tid * 16, dh + 8192);
        gload16(wimg_lo + tid * 16,        dl);
        gload16(wimg_lo + 8192 + tid * 16, dl + 8192);
        float4 a = *(const float4*)(xsrc);
        float4 b = *(const float4*)(xsrc + 4);
        uint4 h, l;
        tsplit2(a.x, a.y, h.x, l.x); tsplit2(a.z, a.w, h.y, l.y);
        tsplit2(b.x, b.y, h.z, l.z); tsplit2(b.z, b.w, h.w, l.w);
        *(uint4*)(smem + XB0 + xwoff)         = h;
        *(uint4*)(smem + XB0 + XHALF + xwoff) = l;
    }
    asm volatile("s_waitcnt vmcnt(0) lgkmcnt(0)" ::: "memory");
    __builtin_amdgcn_sched_barrier(0);
    __builtin_amdgcn_s_barrier();
    __builtin_amdgcn_sched_barrier(0);

#pragma unroll 1
    for (int c = 0; c < NCHUNK; ++c) {
        const char* xb  = smem + ((c & 1) ? XB1 : XB0);
        char*       xbn = smem + ((c & 1) ? XB0 : XB1);
        const bool more = (c + 1 < NCHUNK);

        // ---- A-frags: 4 rf x (hi,lo) from padded x LDS ----
        bf16x8 ah[4], al[4];
#pragma unroll
        for (int rf = 0; rf < 4; ++rf) {
            int ao = hi4 * XSEG + (wr * 64 + rf * 16 + col16) * 16;
            ah[rf] = *(const bf16x8*)(xb + ao);
            al[rf] = *(const bf16x8*)(xb + XHALF + ao);
        }
        // ---- MFMA: cf-outer, 12 per cf ----
#pragma unroll
        for (int cf = 0; cf < 4; ++cf) {
            int bo = hi4 * 4096 + (wc * 64 + cf * 16 + col16) * 16;
            bf16x8 bh = *(const bf16x8*)(smem + WBUF + bo);
            bf16x8 bl = *(const bf16x8*)(smem + WBUF + 16384 + bo);
#pragma unroll
            for (int rf = 0; rf < 4; ++rf) {
                acc[rf][cf] = MFMA_BF16(ah[rf], bh, acc[rf][cf]);
                acc[rf][cf] = MFMA_BF16(al[rf], bh, acc[rf][cf]);
                acc[rf][cf] = MFMA_BF16(ah[rf], bl, acc[rf][cf]);
            }
        }

        // ---- stage x(c+1) into the other buffer ----
        if (more) {
            float4 a = *(const float4*)(xsrc + (c + 1) * BK);
            float4 b = *(const float4*)(xsrc + (c + 1) * BK + 4);
            uint4 h, l;
            tsplit2(a.x, a.y, h.x, l.x); tsplit2(a.z, a.w, h.y, l.y);
            tsplit2(b.x, b.y, h.z, l.z); tsplit2(b.z, b.w, h.w, l.w);
            *(uint4*)(xbn + xwoff)         = h;
            *(uint4*)(xbn + XHALF + xwoff) = l;
        }
        // bar A: all W(c)/x(c) reads consumed + my x writes visible
        asm volatile("s_waitcnt lgkmcnt(0)" ::: "memory");
        __builtin_amdgcn_sched_barrier(0);
        __builtin_amdgcn_s_barrier();
        __builtin_amdgcn_sched_barrier(0);

        if (more) {
            // ---- stage W(c+1) into the (now fully-read) single buffer ----
            const char* gh = wimg_hi + (size_t)(c + 1) * 16384;
            const char* gl = wimg_lo + (size_t)(c + 1) * 16384;
            char* dh = smem + WBUF + w * 1024;
            char* dl = dh + 16384;
            gload16(gh + tid * 16,        dh);
            gload16(gh + 8192 + tid * 16, dh + 8192);
            gload16(gl + tid * 16,        dl);
            gload16(gl + 8192 + tid * 16, dl + 8192);
            // bar B: W(c+1) DMA complete
            asm volatile("s_waitcnt vmcnt(0)" ::: "memory");
            __builtin_amdgcn_sched_barrier(0);
            __builtin_amdgcn_s_barrier();
            __builtin_amdgcn_sched_barrier(0);
        }
    }

    // ---- epilogue: prob = sigmoid(beta*(logit+b)) -> u16 LDS [128][PSTR] ----
    unsigned short* prob = (unsigned short*)smem;
    {
        float bb[4], bt[4];
#pragma unroll
        for (int cf = 0; cf < 4; ++cf) {
            int col = wc * 64 + cf * 16 + col16;
            bb[cf] = (col < N_INNER) ? bv[col]   : 0.f;
            bt[cf] = (col < N_INNER) ? beta[col] : 0.f;
        }
#pragma unroll
        for (int rf = 0; rf < 4; ++rf)
#pragma unroll
            for (int cf = 0; cf < 4; ++cf) {
                int col = wc * 64 + cf * 16 + col16;
#pragma unroll
                for (int r = 0; r < 4; ++r) {
                    int row = wr * 64 + rf * 16 + hi4 * 4 + r;
                    float t = (acc[rf][cf][r] + bb[cf]) * bt[cf];
                    float s = 1.f / (1.f + __expf(-t));
                    float u = fminf(s * 65536.f + 0.5f, 65535.f);
                    prob[row * PSTR + col] = (unsigned short)(unsigned)u;
                }
            }
    }
    __syncthreads();                 // B0: prob visible

    // ---- tree expansion: 4 threads/row, 64 leaves each ----
    const int prow = tid >> 2;           // 0..127
    const int qq   = tid & 3;            // top-2 leaf bits
    const unsigned short* pb = prob + prow * PSTR;
    float P[64];
    {
        float p0 = (float)pb[0] * INV64K;             float f0 = (qq & 2) ? (1.f - p0) : p0;
        float p1 = (float)pb[1 + (qq >> 1)] * INV64K; float f1 = (qq & 1) ? (1.f - p1) : p1;
        P[0] = f0 * f1;
    }
    TREE_STAGE(2) TREE_STAGE(3) TREE_STAGE(4) TREE_STAGE(5) TREE_STAGE(6) TREE_STAGE(7)

    // p -> global (output 1): 64 contiguous floats per thread
    {
        float* po = out + OUT_HDR + (size_t)(row0 + prow) * N_LEAF + qq * 64;
#pragma unroll
        for (int m = 0; m < 16; ++m)
            *(float4*)(po + m * 4) = make_float4(P[4*m], P[4*m+1], P[4*m+2], P[4*m+3]);
    }
    __syncthreads();                 // B1: all prob reads done

    // ---- P hi-image overlaying prob: [kc 8][koct 4][row 128][16B] + qq*32 skew ----
#pragma unroll
    for (int kk = 0; kk < 2; ++kk)
#pragma unroll
        for (int g = 0; g < 4; ++g) {
            int b = kk * 32 + g * 8;
            uint4 h;
            h.x = packhi2(P[b+0], P[b+1]);
            h.y = packhi2(P[b+2], P[b+3]);
            h.z = packhi2(P[b+4], P[b+5]);
            h.w = packhi2(P[b+6], P[b+7]);
            *(uint4*)(smem + (2*qq + kk) * 8192 + g * 2048 + prow * 16 + qq * 32) = h;
        }
    __syncthreads();                 // B2: hi image visible

    // ---- out = p @ Q via MFMA; wave w owns rows w*16..w*16+15, cols 0..31 ----
    f32x4 acc2[2];
    acc2[0] = (f32x4){0.f,0.f,0.f,0.f};
    acc2[1] = (f32x4){0.f,0.f,0.f,0.f};
    const int arow = w * 16 + col16;

    // pass A: P_hi x (Q_hi + Q_lo)
#pragma unroll
    for (int kc = 0; kc < 8; ++kc) {
        bf16x8 pa = *(const bf16x8*)(smem + kc * 8192 + hi4 * 2048 + arow * 16 + (kc >> 1) * 32);
#pragma unroll
        for (int cf = 0; cf < 2; ++cf) {
            int qo = (cf * 16 + col16) * 256 + kc * 32 + hi4 * 8;
            bf16x8 qbh = *(const bf16x8*)(qhi + qo);
            bf16x8 qbl = *(const bf16x8*)(qlo + qo);
            acc2[cf] = MFMA_BF16(pa, qbh, acc2[cf]);
            acc2[cf] = MFMA_BF16(pa, qbl, acc2[cf]);
        }
    }
    __syncthreads();                 // B3: P_hi reads done

    // ---- P lo-image overwrite ----
#pragma unroll
    for (int kk = 0; kk < 2; ++kk)
#pragma unroll
        for (int g = 0; g < 4; ++g) {
            int b = kk * 32 + g * 8;
            uint4 l;
            l.x = packlo2(P[b+0], P[b+1]);
            l.y = packlo2(P[b+2], P[b+3]);
            l.z = packlo2(P[b+4], P[b+5]);
            l.w = packlo2(P[b+6], P[b+7]);
            *(uint4*)(smem + (2*qq + kk) * 8192 + g * 2048 + prow * 16 + qq * 32) = l;
        }
    __syncthreads();                 // B4

    // pass B: P_lo x Q_hi, then store out
#pragma unroll
    for (int kc = 0; kc < 8; ++kc) {
        bf16x8 pl = *(const bf16x8*)(smem + kc * 8192 + hi4 * 2048 + arow * 16 + (kc >> 1) * 32);
#pragma unroll
        for (int cf = 0; cf < 2; ++cf) {
            int qo = (cf * 16 + col16) * 256 + kc * 32 + hi4 * 8;
            bf16x8 qbh = *(const bf16x8*)(qhi + qo);
            acc2[cf] = MFMA_BF16(pl, qbh, acc2[cf]);
        }
    }
#pragma unroll
    for (int cf = 0; cf < 2; ++cf)
#pragma unroll
        for (int r = 0; r < 4; ++r) {
            int row = w * 16 + hi4 * 4 + r;
            out[(size_t)(row0 + row) * OUT_DIM + cf * 16 + col16] = acc2[cf][r];
        }
}

extern "C" void kernel_launch(void* const* d_in, const int* in_sizes, int n_in,
                              void* d_out, int out_size, void* d_ws, size_t ws_size,
                              hipStream_t stream) {
    const float* x    = (const float*)d_in[0];
    const float* W    = (const float*)d_in[1];
    const float* bv   = (const float*)d_in[2];
    const float* beta = (const float*)d_in[3];
    const float* leaf = (const float*)d_in[4];
    float* out = (float*)d_out;
    char* ws = (char*)d_ws;

    unsigned short* qhi = (unsigned short*)(ws + WS_QT_HI);
    unsigned short* qlo = (unsigned short*)(ws + WS_QT_LO);
    char* whi = ws + WS_WIMG_HI;
    char* wlo = ws + WS_WIMG_LO;

    hipFuncSetAttribute(reinterpret_cast<const void*>(tree_k),
                        hipFuncAttributeMaxDynamicSharedMemorySize, SMEM_BYTES);

    wsplit_k<<<16, 512, 0, stream>>>(W, (unsigned int*)whi, (unsigned int*)wlo);
    qt_k<<<1, 256, 0, stream>>>(leaf, qhi, qlo);
    tree_k<<<BATCH / TILE_M, NTHR, SMEM_BYTES, stream>>>(
        x, bv, beta, qhi, qlo, whi, wlo, out);
}

// Round 11
// 145.161 us; speedup vs baseline: 1.2221x; 1.0212x over previous
//
#include <hip/hip_runtime.h>

#define BATCH   131072
#define IN_DIM  256
#define OUT_DIM 32
#define N_INNER 255
#define N_LEAF  256
#define OUT_HDR (BATCH * OUT_DIM)

#define TILE_M  128
#define BK      32
#define NTHR    512
#define NCHUNK  8
#define PSTR    260                      // u16; hi4 row-group step 4*520=2080 = 32 mod 128 -> disjoint bank windows
#define INV64K  (1.0f / 65536.0f)

// ---- d_ws layout (bytes) ----
#define WS_QT_HI   0                     // [32 cols][256 leaves] bf16
#define WS_QT_LO   16384
#define WS_WIMG_HI 32768                 // [8 chunk][4 kg][256 node][16B] bf16-hi
#define WS_WIMG_LO (32768 + 131072)      // same layout, bf16-lo

// ---- LDS layout (bytes) ----
// WBUF  [0, 32768)      W single buffer: hi 16K ([kg][node][16B]) + lo 16K
// XB0   [32768, 49408)  x buf 0: hi 4x2080 + lo 4x2080 (padded segs)
// XB1   [49408, 66048)  x buf 1
// tail overlays: prob u16 [128][PSTR] at 0 (66560B); P image [0,65536) in two passes
#define WBUF 0
#define XSEG 2080
#define XHALF 8320                       // 4*XSEG
#define XB0   32768
#define XB1   49408
#define SMEM_BYTES 69632                 // -> 2 blocks/CU

typedef __attribute__((ext_vector_type(8))) short bf16x8;
typedef __attribute__((ext_vector_type(4))) float f32x4;

__device__ __forceinline__ unsigned short bf16rne(float a) {
    unsigned u = __float_as_uint(a);
    return (unsigned short)((u + 0x7FFFu + ((u >> 16) & 1u)) >> 16);
}
__device__ __forceinline__ unsigned packhi2(float a, float b) {
    return (unsigned)bf16rne(a) | ((unsigned)bf16rne(b) << 16);
}
__device__ __forceinline__ unsigned packlo2(float a, float b) {
    unsigned short ha = bf16rne(a), hb = bf16rne(b);
    float ra = a - __uint_as_float((unsigned)ha << 16);
    float rb = b - __uint_as_float((unsigned)hb << 16);
    return (unsigned)bf16rne(ra) | ((unsigned)bf16rne(rb) << 16);
}
__device__ __forceinline__ void split2(float a, float b, unsigned& hi, unsigned& lo) {
    unsigned short ha = bf16rne(a), hb = bf16rne(b);
    hi = (unsigned)ha | ((unsigned)hb << 16);
    float ra = a - __uint_as_float((unsigned)ha << 16);
    float rb = b - __uint_as_float((unsigned)hb << 16);
    lo = (unsigned)bf16rne(ra) | ((unsigned)bf16rne(rb) << 16);
}
// cheap trunc split (numerically verified rounds 1-9)
__device__ __forceinline__ void tsplit2(float a, float b, unsigned& h, unsigned& l) {
    unsigned ua = __float_as_uint(a), ub = __float_as_uint(b);
    h = (ua >> 16) | (ub & 0xFFFF0000u);
    float ra = a - __uint_as_float(ua & 0xFFFF0000u);
    float rb = b - __uint_as_float(ub & 0xFFFF0000u);
    l = (__float_as_uint(ra) >> 16) | (__float_as_uint(rb) & 0xFFFF0000u);
}

__device__ __forceinline__ void gload16(const void* g, void* l) {
    __builtin_amdgcn_global_load_lds(
        (const __attribute__((address_space(1))) unsigned int*)g,
        (__attribute__((address_space(3))) unsigned int*)l, 16, 0, 0);
}

// ---------------- setup: W -> hi/lo bf16 chunk images ----------------
__global__ void wsplit_k(const float* __restrict__ W,
                         unsigned int* __restrict__ whi, unsigned int* __restrict__ wlo) {
    int gid = blockIdx.x * 512 + threadIdx.x;      // 0..8191
    int n   = gid >> 5;                            // node 0..255
    int oct = gid & 31;                            // k-octet
    float4 a = make_float4(0.f,0.f,0.f,0.f), b = a;
    if (n < N_INNER) {
        a = *(const float4*)(W + (size_t)n * IN_DIM + oct * 8);
        b = *(const float4*)(W + (size_t)n * IN_DIM + oct * 8 + 4);
    }
    uint4 h, l;
    split2(a.x, a.y, h.x, l.x); split2(a.z, a.w, h.y, l.y);
    split2(b.x, b.y, h.z, l.z); split2(b.z, b.w, h.w, l.w);
    int c = oct >> 2, kg = oct & 3;
    size_t off = ((size_t)(c * 4 + kg) * 256 + n) * 4;   // uints
    *(uint4*)(whi + off) = h;
    *(uint4*)(wlo + off) = l;
}

// ---------------- setup: Q = softmax(leaf), transposed hi/lo bf16 ----------------
__global__ void qt_k(const float* __restrict__ leaf,
                     unsigned short* __restrict__ qhi, unsigned short* __restrict__ qlo) {
    int l = threadIdx.x;                           // leaf 0..255
    const float* row = leaf + l * OUT_DIM;
    float v[OUT_DIM];
    float mx = -1e30f;
#pragma unroll
    for (int o = 0; o < OUT_DIM; ++o) { v[o] = row[o]; mx = fmaxf(mx, v[o]); }
    float s = 0.f;
#pragma unroll
    for (int o = 0; o < OUT_DIM; ++o) { v[o] = __expf(v[o] - mx); s += v[o]; }
    float r = 1.f / s;
#pragma unroll
    for (int o = 0; o < OUT_DIM; ++o) {
        float q = v[o] * r;
        unsigned short h = bf16rne(q);
        float res = q - __uint_as_float((unsigned)h << 16);
        qhi[o * 256 + l] = h;
        qlo[o * 256 + l] = bf16rne(res);
    }
}

// tree DP stage, qq = top-2 leaf bits (4 threads/row, 64 leaves each)
#define TREE_STAGE(D) { \
    const int base_ = (1 << (D)) - 1 + (qq << ((D) - 2)); \
    _Pragma("unroll") \
    for (int i = (1 << ((D) - 2)) - 1; i >= 0; --i) { \
        float pr_ = (float)pb[base_ + i] * INV64K; \
        float a_  = P[i]; \
        float lv_ = a_ * pr_; \
        P[2*i]     = lv_; \
        P[2*i + 1] = a_ - lv_; \
    } }

#define MFMA_BF16(A, B, C) __builtin_amdgcn_mfma_f32_16x16x32_bf16(A, B, C, 0, 0, 0)

// ---------------- fused main kernel ----------------
// R9 (proven 147.6/148.2us) + exactly two isolated deltas:
//   (1) PSTR 272->260: prob-write bank-conflict fix (disjoint hi4 windows)
//   (2) rcp sigmoid: err ~2^-22 << u16 quant step 2^-16
__launch_bounds__(NTHR, 4)
__global__ void tree_k(const float* __restrict__ x,
                       const float* __restrict__ bv, const float* __restrict__ beta,
                       const unsigned short* __restrict__ qhi, const unsigned short* __restrict__ qlo,
                       const char* __restrict__ wimg_hi, const char* __restrict__ wimg_lo,
                       float* __restrict__ out) {
    extern __shared__ char smem[];
    const int tid  = threadIdx.x;
    const int row0 = blockIdx.x * TILE_M;

    const int lane  = tid & 63;
    const int w     = tid >> 6;          // wave 0..7
    const int col16 = lane & 15;
    const int hi4   = lane >> 4;         // k-octet 0..3
    const int wr    = w >> 2;            // row half (0..1)
    const int wc    = w & 3;             // col group (0..3)

    f32x4 acc[4][4];
#pragma unroll
    for (int i = 0; i < 4; ++i)
#pragma unroll
        for (int j = 0; j < 4; ++j) acc[i][j] = (f32x4){0.f, 0.f, 0.f, 0.f};

    const int xrow = tid >> 2;           // 0..127
    const int xk   = tid & 3;            // k-octet staged by this thread
    const int xwoff = xk * XSEG + xrow * 16;
    const float* xsrc = x + (size_t)(row0 + xrow) * IN_DIM + xk * 8;

    // ---- prologue: stage W(0) + x(0) ----
    {
        char* dh = smem + WBUF + w * 1024;
        char* dl = dh + 16384;
        gload16(wimg_hi + tid * 16,        dh);
        gload16(wimg_hi + 8192 + tid * 16, dh + 8192);
        gload16(wimg_lo + tid * 16,        dl);
        gload16(wimg_lo + 8192 + tid * 16, dl + 8192);
        float4 a = *(const float4*)(xsrc);
        float4 b = *(const float4*)(xsrc + 4);
        uint4 h, l;
        tsplit2(a.x, a.y, h.x, l.x); tsplit2(a.z, a.w, h.y, l.y);
        tsplit2(b.x, b.y, h.z, l.z); tsplit2(b.z, b.w, h.w, l.w);
        *(uint4*)(smem + XB0 + xwoff)         = h;
        *(uint4*)(smem + XB0 + XHALF + xwoff) = l;
    }
    asm volatile("s_waitcnt vmcnt(0) lgkmcnt(0)" ::: "memory");
    __builtin_amdgcn_sched_barrier(0);
    __builtin_amdgcn_s_barrier();
    __builtin_amdgcn_sched_barrier(0);

#pragma unroll 1
    for (int c = 0; c < NCHUNK; ++c) {
        const char* xb  = smem + ((c & 1) ? XB1 : XB0);
        char*       xbn = smem + ((c & 1) ? XB0 : XB1);
        const bool more = (c + 1 < NCHUNK);

        // ---- A-frags: 4 rf x (hi,lo) from padded x LDS ----
        bf16x8 ah[4], al[4];
#pragma unroll
        for (int rf = 0; rf < 4; ++rf) {
            int ao = hi4 * XSEG + (wr * 64 + rf * 16 + col16) * 16;
            ah[rf] = *(const bf16x8*)(xb + ao);
            al[rf] = *(const bf16x8*)(xb + XHALF + ao);
        }
        // ---- MFMA: cf-outer, 12 per cf ----
#pragma unroll
        for (int cf = 0; cf < 4; ++cf) {
            int bo = hi4 * 4096 + (wc * 64 + cf * 16 + col16) * 16;
            bf16x8 bh = *(const bf16x8*)(smem + WBUF + bo);
            bf16x8 bl = *(const bf16x8*)(smem + WBUF + 16384 + bo);
#pragma unroll
            for (int rf = 0; rf < 4; ++rf) {
                acc[rf][cf] = MFMA_BF16(ah[rf], bh, acc[rf][cf]);
                acc[rf][cf] = MFMA_BF16(al[rf], bh, acc[rf][cf]);
                acc[rf][cf] = MFMA_BF16(ah[rf], bl, acc[rf][cf]);
            }
        }

        // ---- stage x(c+1) into the other buffer ----
        if (more) {
            float4 a = *(const float4*)(xsrc + (c + 1) * BK);
            float4 b = *(const float4*)(xsrc + (c + 1) * BK + 4);
            uint4 h, l;
            tsplit2(a.x, a.y, h.x, l.x); tsplit2(a.z, a.w, h.y, l.y);
            tsplit2(b.x, b.y, h.z, l.z); tsplit2(b.z, b.w, h.w, l.w);
            *(uint4*)(xbn + xwoff)         = h;
            *(uint4*)(xbn + XHALF + xwoff) = l;
        }
        // bar A: all W(c)/x(c) reads consumed + my x writes visible
        asm volatile("s_waitcnt lgkmcnt(0)" ::: "memory");
        __builtin_amdgcn_sched_barrier(0);
        __builtin_amdgcn_s_barrier();
        __builtin_amdgcn_sched_barrier(0);

        if (more) {
            // ---- stage W(c+1) into the (now fully-read) single buffer ----
            const char* gh = wimg_hi + (size_t)(c + 1) * 16384;
            const char* gl = wimg_lo + (size_t)(c + 1) * 16384;
            char* dh = smem + WBUF + w * 1024;
            char* dl = dh + 16384;
            gload16(gh + tid * 16,        dh);
            gload16(gh + 8192 + tid * 16, dh + 8192);
            gload16(gl + tid * 16,        dl);
            gload16(gl + 8192 + tid * 16, dl + 8192);
            // bar B: W(c+1) DMA complete
            asm volatile("s_waitcnt vmcnt(0)" ::: "memory");
            __builtin_amdgcn_sched_barrier(0);
            __builtin_amdgcn_s_barrier();
            __builtin_amdgcn_sched_barrier(0);
        }
    }

    // ---- epilogue: prob = sigmoid(beta*(logit+b)) -> u16 LDS [128][PSTR] ----
    unsigned short* prob = (unsigned short*)smem;
    {
        float bb[4], bt[4];
#pragma unroll
        for (int cf = 0; cf < 4; ++cf) {
            int col = wc * 64 + cf * 16 + col16;
            bb[cf] = (col < N_INNER) ? bv[col]   : 0.f;
            bt[cf] = (col < N_INNER) ? beta[col] : 0.f;
        }
#pragma unroll
        for (int rf = 0; rf < 4; ++rf)
#pragma unroll
            for (int cf = 0; cf < 4; ++cf) {
                int col = wc * 64 + cf * 16 + col16;
#pragma unroll
                for (int r = 0; r < 4; ++r) {
                    int row = wr * 64 + rf * 16 + hi4 * 4 + r;
                    float t = (acc[rf][cf][r] + bb[cf]) * bt[cf];
                    // s = 1/(1+e^-t); rcp err ~2^-22 << u16 quant step 2^-16
                    float s = __builtin_amdgcn_rcpf(1.f + __expf(-t));
                    float u = fminf(s * 65536.f + 0.5f, 65535.f);
                    prob[row * PSTR + col] = (unsigned short)(unsigned)u;
                }
            }
    }
    __syncthreads();                 // B0: prob visible

    // ---- tree expansion: 4 threads/row, 64 leaves each ----
    const int prow = tid >> 2;           // 0..127
    const int qq   = tid & 3;            // top-2 leaf bits
    const unsigned short* pb = prob + prow * PSTR;
    float P[64];
    {
        float p0 = (float)pb[0] * INV64K;             float f0 = (qq & 2) ? (1.f - p0) : p0;
        float p1 = (float)pb[1 + (qq >> 1)] * INV64K; float f1 = (qq & 1) ? (1.f - p1) : p1;
        P[0] = f0 * f1;
    }
    TREE_STAGE(2) TREE_STAGE(3) TREE_STAGE(4) TREE_STAGE(5) TREE_STAGE(6) TREE_STAGE(7)

    // p -> global (output 1): 64 contiguous floats per thread
    {
        float* po = out + OUT_HDR + (size_t)(row0 + prow) * N_LEAF + qq * 64;
#pragma unroll
        for (int m = 0; m < 16; ++m)
            *(float4*)(po + m * 4) = make_float4(P[4*m], P[4*m+1], P[4*m+2], P[4*m+3]);
    }
    __syncthreads();                 // B1: all prob reads done

    // ---- P hi-image overlaying prob: [kc 8][koct 4][row 128][16B] + qq*32 skew ----
#pragma unroll
    for (int kk = 0; kk < 2; ++kk)
#pragma unroll
        for (int g = 0; g < 4; ++g) {
            int b = kk * 32 + g * 8;
            uint4 h;
            h.x = packhi2(P[b+0], P[b+1]);
            h.y = packhi2(P[b+2], P[b+3]);
            h.z = packhi2(P[b+4], P[b+5]);
            h.w = packhi2(P[b+6], P[b+7]);
            *(uint4*)(smem + (2*qq + kk) * 8192 + g * 2048 + prow * 16 + qq * 32) = h;
        }
    __syncthreads();                 // B2: hi image visible

    // ---- out = p @ Q via MFMA; wave w owns rows w*16..w*16+15, cols 0..31 ----
    f32x4 acc2[2];
    acc2[0] = (f32x4){0.f,0.f,0.f,0.f};
    acc2[1] = (f32x4){0.f,0.f,0.f,0.f};
    const int arow = w * 16 + col16;

    // pass A: P_hi x (Q_hi + Q_lo)
#pragma unroll
    for (int kc = 0; kc < 8; ++kc) {
        bf16x8 pa = *(const bf16x8*)(smem + kc * 8192 + hi4 * 2048 + arow * 16 + (kc >> 1) * 32);
#pragma unroll
        for (int cf = 0; cf < 2; ++cf) {
            int qo = (cf * 16 + col16) * 256 + kc * 32 + hi4 * 8;
            bf16x8 qbh = *(const bf16x8*)(qhi + qo);
            bf16x8 qbl = *(const bf16x8*)(qlo + qo);
            acc2[cf] = MFMA_BF16(pa, qbh, acc2[cf]);
            acc2[cf] = MFMA_BF16(pa, qbl, acc2[cf]);
        }
    }
    __syncthreads();                 // B3: P_hi reads done

    // ---- P lo-image overwrite ----
#pragma unroll
    for (int kk = 0; kk < 2; ++kk)
#pragma unroll
        for (int g = 0; g < 4; ++g) {
            int b = kk * 32 + g * 8;
            uint4 l;
            l.x = packlo2(P[b+0], P[b+1]);
            l.y = packlo2(P[b+2], P[b+3]);
            l.z = packlo2(P[b+4], P[b+5]);
            l.w = packlo2(P[b+6], P[b+7]);
            *(uint4*)(smem + (2*qq + kk) * 8192 + g * 2048 + prow * 16 + qq * 32) = l;
        }
    __syncthreads();                 // B4

    // pass B: P_lo x Q_hi, then store out
#pragma unroll
    for (int kc = 0; kc < 8; ++kc) {
        bf16x8 pl = *(const bf16x8*)(smem + kc * 8192 + hi4 * 2048 + arow * 16 + (kc >> 1) * 32);
#pragma unroll
        for (int cf = 0; cf < 2; ++cf) {
            int qo = (cf * 16 + col16) * 256 + kc * 32 + hi4 * 8;
            bf16x8 qbh = *(const bf16x8*)(qhi + qo);
            acc2[cf] = MFMA_BF16(pl, qbh, acc2[cf]);
        }
    }
#pragma unroll
    for (int cf = 0; cf < 2; ++cf)
#pragma unroll
        for (int r = 0; r < 4; ++r) {
            int row = w * 16 + hi4 * 4 + r;
            out[(size_t)(row0 + row) * OUT_DIM + cf * 16 + col16] = acc2[cf][r];
        }
}

extern "C" void kernel_launch(void* const* d_in, const int* in_sizes, int n_in,
                              void* d_out, int out_size, void* d_ws, size_t ws_size,
                              hipStream_t stream) {
    const float* x    = (const float*)d_in[0];
    const float* W    = (const float*)d_in[1];
    const float* bv   = (const float*)d_in[2];
    const float* beta = (const float*)d_in[3];
    const float* leaf = (const float*)d_in[4];
    float* out = (float*)d_out;
    char* ws = (char*)d_ws;

    unsigned short* qhi = (unsigned short*)(ws + WS_QT_HI);
    unsigned short* qlo = (unsigned short*)(ws + WS_QT_LO);
    char* whi = ws + WS_WIMG_HI;
    char* wlo = ws + WS_WIMG_LO;

    hipFuncSetAttribute(reinterpret_cast<const void*>(tree_k),
                        hipFuncAttributeMaxDynamicSharedMemorySize, SMEM_BYTES);

    wsplit_k<<<16, 512, 0, stream>>>(W, (unsigned int*)whi, (unsigned int*)wlo);
    qt_k<<<1, 256, 0, stream>>>(leaf, qhi, qlo);
    tree_k<<<BATCH / TILE_M, NTHR, SMEM_BYTES, stream>>>(
        x, bv, beta, qhi, qlo, whi, wlo, out);
}

// Round 12
// 144.251 us; speedup vs baseline: 1.2298x; 1.0063x over previous
//
#include <hip/hip_runtime.h>

#define BATCH   131072
#define IN_DIM  256
#define OUT_DIM 32
#define N_INNER 255
#define N_LEAF  256
#define OUT_HDR (BATCH * OUT_DIM)

#define TILE_M  128
#define BK      32
#define NTHR    512
#define NCHUNK  8
#define PSTR    260                      // u16; hi4 row-group step 4*520=2080 = 32 mod 128 -> disjoint bank windows
#define INV64K  (1.0f / 65536.0f)

// ---- d_ws layout (bytes) ----
#define WS_QT_HI   0                     // [32 cols][256 leaves] bf16
#define WS_QT_LO   16384
#define WS_WIMG_HI 32768                 // [8 chunk][4 kg][256 node][16B] bf16-hi
#define WS_WIMG_LO (32768 + 131072)      // same layout, bf16-lo

// ---- LDS layout (bytes) ----
// W buffer with PADDED kg segments: WSEG = 4096+32 -> kg groups at 0/32/64/96
// mod 128 (disjoint bank windows on ds_read, same pattern as x's XSEG).
//   hi: 4 segs [0, 16512);  lo: 4 segs [16512, 33024)
// XB0   [33024, 49664)  x buf 0: hi 4x2080 + lo 4x2080 (padded segs)
// XB1   [49664, 66304)  x buf 1
// tail overlays: prob u16 [128][PSTR] at 0 (66560B); P image [0,65616) in two passes
#define WSEG  4128
#define WLO   (4 * WSEG)                 // 16512: lo-half base
#define XSEG  2080
#define XHALF 8320                       // 4*XSEG
#define XB0   33024
#define XB1   49664
#define SMEM_BYTES 69632                 // -> 2 blocks/CU (unchanged)

typedef __attribute__((ext_vector_type(8))) short bf16x8;
typedef __attribute__((ext_vector_type(4))) float f32x4;

__device__ __forceinline__ unsigned short bf16rne(float a) {
    unsigned u = __float_as_uint(a);
    return (unsigned short)((u + 0x7FFFu + ((u >> 16) & 1u)) >> 16);
}
__device__ __forceinline__ unsigned packhi2(float a, float b) {
    return (unsigned)bf16rne(a) | ((unsigned)bf16rne(b) << 16);
}
__device__ __forceinline__ unsigned packlo2(float a, float b) {
    unsigned short ha = bf16rne(a), hb = bf16rne(b);
    float ra = a - __uint_as_float((unsigned)ha << 16);
    float rb = b - __uint_as_float((unsigned)hb << 16);
    return (unsigned)bf16rne(ra) | ((unsigned)bf16rne(rb) << 16);
}
__device__ __forceinline__ void split2(float a, float b, unsigned& hi, unsigned& lo) {
    unsigned short ha = bf16rne(a), hb = bf16rne(b);
    hi = (unsigned)ha | ((unsigned)hb << 16);
    float ra = a - __uint_as_float((unsigned)ha << 16);
    float rb = b - __uint_as_float((unsigned)hb << 16);
    lo = (unsigned)bf16rne(ra) | ((unsigned)bf16rne(rb) << 16);
}
// cheap trunc split (numerically verified rounds 1-11)
__device__ __forceinline__ void tsplit2(float a, float b, unsigned& h, unsigned& l) {
    unsigned ua = __float_as_uint(a), ub = __float_as_uint(b);
    h = (ua >> 16) | (ub & 0xFFFF0000u);
    float ra = a - __uint_as_float(ua & 0xFFFF0000u);
    float rb = b - __uint_as_float(ub & 0xFFFF0000u);
    l = (__float_as_uint(ra) >> 16) | (__float_as_uint(rb) & 0xFFFF0000u);
}

__device__ __forceinline__ void gload16(const void* g, void* l) {
    __builtin_amdgcn_global_load_lds(
        (const __attribute__((address_space(1))) unsigned int*)g,
        (__attribute__((address_space(3))) unsigned int*)l, 16, 0, 0);
}

// ---------------- setup: W -> hi/lo bf16 chunk images ----------------
__global__ void wsplit_k(const float* __restrict__ W,
                         unsigned int* __restrict__ whi, unsigned int* __restrict__ wlo) {
    int gid = blockIdx.x * 512 + threadIdx.x;      // 0..8191
    int n   = gid >> 5;                            // node 0..255
    int oct = gid & 31;                            // k-octet
    float4 a = make_float4(0.f,0.f,0.f,0.f), b = a;
    if (n < N_INNER) {
        a = *(const float4*)(W + (size_t)n * IN_DIM + oct * 8);
        b = *(const float4*)(W + (size_t)n * IN_DIM + oct * 8 + 4);
    }
    uint4 h, l;
    split2(a.x, a.y, h.x, l.x); split2(a.z, a.w, h.y, l.y);
    split2(b.x, b.y, h.z, l.z); split2(b.z, b.w, h.w, l.w);
    int c = oct >> 2, kg = oct & 3;
    size_t off = ((size_t)(c * 4 + kg) * 256 + n) * 4;   // uints
    *(uint4*)(whi + off) = h;
    *(uint4*)(wlo + off) = l;
}

// ---------------- setup: Q = softmax(leaf), transposed hi/lo bf16 ----------------
__global__ void qt_k(const float* __restrict__ leaf,
                     unsigned short* __restrict__ qhi, unsigned short* __restrict__ qlo) {
    int l = threadIdx.x;                           // leaf 0..255
    const float* row = leaf + l * OUT_DIM;
    float v[OUT_DIM];
    float mx = -1e30f;
#pragma unroll
    for (int o = 0; o < OUT_DIM; ++o) { v[o] = row[o]; mx = fmaxf(mx, v[o]); }
    float s = 0.f;
#pragma unroll
    for (int o = 0; o < OUT_DIM; ++o) { v[o] = __expf(v[o] - mx); s += v[o]; }
    float r = 1.f / s;
#pragma unroll
    for (int o = 0; o < OUT_DIM; ++o) {
        float q = v[o] * r;
        unsigned short h = bf16rne(q);
        float res = q - __uint_as_float((unsigned)h << 16);
        qhi[o * 256 + l] = h;
        qlo[o * 256 + l] = bf16rne(res);
    }
}

// tree DP stage, qq = top-2 leaf bits (4 threads/row, 64 leaves each)
#define TREE_STAGE(D) { \
    const int base_ = (1 << (D)) - 1 + (qq << ((D) - 2)); \
    _Pragma("unroll") \
    for (int i = (1 << ((D) - 2)) - 1; i >= 0; --i) { \
        float pr_ = (float)pb[base_ + i] * INV64K; \
        float a_  = P[i]; \
        float lv_ = a_ * pr_; \
        P[2*i]     = lv_; \
        P[2*i + 1] = a_ - lv_; \
    } }

#define MFMA_BF16(A, B, C) __builtin_amdgcn_mfma_f32_16x16x32_bf16(A, B, C, 0, 0, 0)

// ---------------- fused main kernel ----------------
// R11 (proven 145.2us) + one isolated delta: padded W kg-segments (WSEG=4128)
// so the 4 hi4 lane-groups of every W ds_read_b128 hit disjoint bank windows
// (0/32/64/96 mod 128), matching the x-buffer design. DMA dests remain
// wave-uniform-base + lane*16 within a single segment.
__launch_bounds__(NTHR, 4)
__global__ void tree_k(const float* __restrict__ x,
                       const float* __restrict__ bv, const float* __restrict__ beta,
                       const unsigned short* __restrict__ qhi, const unsigned short* __restrict__ qlo,
                       const char* __restrict__ wimg_hi, const char* __restrict__ wimg_lo,
                       float* __restrict__ out) {
    extern __shared__ char smem[];
    const int tid  = threadIdx.x;
    const int row0 = blockIdx.x * TILE_M;

    const int lane  = tid & 63;
    const int w     = tid >> 6;          // wave 0..7
    const int col16 = lane & 15;
    const int hi4   = lane >> 4;         // k-octet 0..3
    const int wr    = w >> 2;            // row half (0..1)
    const int wc    = w & 3;             // col group (0..3)

    f32x4 acc[4][4];
#pragma unroll
    for (int i = 0; i < 4; ++i)
#pragma unroll
        for (int j = 0; j < 4; ++j) acc[i][j] = (f32x4){0.f, 0.f, 0.f, 0.f};

    const int xrow = tid >> 2;           // 0..127
    const int xk   = tid & 3;            // k-octet staged by this thread
    const int xwoff = xk * XSEG + xrow * 16;
    const float* xsrc = x + (size_t)(row0 + xrow) * IN_DIM + xk * 8;

    // W stage dests (wave-uniform): first gload covers kg = w>>2, second kg = 2+(w>>2);
    // within-segment offset (w&3)*1024 + lane*16 (max 4096 <= WSEG-32).
    const int wsub = (w & 3) * 1024;
    char* const wdh  = smem + (w >> 2) * WSEG + wsub;
    char* const wdh2 = smem + (2 + (w >> 2)) * WSEG + wsub;

    // ---- prologue: stage W(0) + x(0) ----
    {
        gload16(wimg_hi + tid * 16,        wdh);
        gload16(wimg_hi + 8192 + tid * 16, wdh2);
        gload16(wimg_lo + tid * 16,        wdh + WLO);
        gload16(wimg_lo + 8192 + tid * 16, wdh2 + WLO);
        float4 a = *(const float4*)(xsrc);
        float4 b = *(const float4*)(xsrc + 4);
        uint4 h, l;
        tsplit2(a.x, a.y, h.x, l.x); tsplit2(a.z, a.w, h.y, l.y);
        tsplit2(b.x, b.y, h.z, l.z); tsplit2(b.z, b.w, h.w, l.w);
        *(uint4*)(smem + XB0 + xwoff)         = h;
        *(uint4*)(smem + XB0 + XHALF + xwoff) = l;
    }
    asm volatile("s_waitcnt vmcnt(0) lgkmcnt(0)" ::: "memory");
    __builtin_amdgcn_sched_barrier(0);
    __builtin_amdgcn_s_barrier();
    __builtin_amdgcn_sched_barrier(0);

#pragma unroll 1
    for (int c = 0; c < NCHUNK; ++c) {
        const char* xb  = smem + ((c & 1) ? XB1 : XB0);
        char*       xbn = smem + ((c & 1) ? XB0 : XB1);
        const bool more = (c + 1 < NCHUNK);

        // ---- A-frags: 4 rf x (hi,lo) from padded x LDS ----
        bf16x8 ah[4], al[4];
#pragma unroll
        for (int rf = 0; rf < 4; ++rf) {
            int ao = hi4 * XSEG + (wr * 64 + rf * 16 + col16) * 16;
            ah[rf] = *(const bf16x8*)(xb + ao);
            al[rf] = *(const bf16x8*)(xb + XHALF + ao);
        }
        // ---- MFMA: cf-outer, 12 per cf; W segs padded (WSEG) ----
#pragma unroll
        for (int cf = 0; cf < 4; ++cf) {
            int bo = hi4 * WSEG + (wc * 64 + cf * 16 + col16) * 16;
            bf16x8 bh = *(const bf16x8*)(smem + bo);
            bf16x8 bl = *(const bf16x8*)(smem + WLO + bo);
#pragma unroll
            for (int rf = 0; rf < 4; ++rf) {
                acc[rf][cf] = MFMA_BF16(ah[rf], bh, acc[rf][cf]);
                acc[rf][cf] = MFMA_BF16(al[rf], bh, acc[rf][cf]);
                acc[rf][cf] = MFMA_BF16(ah[rf], bl, acc[rf][cf]);
            }
        }

        // ---- stage x(c+1) into the other buffer ----
        if (more) {
            float4 a = *(const float4*)(xsrc + (c + 1) * BK);
            float4 b = *(const float4*)(xsrc + (c + 1) * BK + 4);
            uint4 h, l;
            tsplit2(a.x, a.y, h.x, l.x); tsplit2(a.z, a.w, h.y, l.y);
            tsplit2(b.x, b.y, h.z, l.z); tsplit2(b.z, b.w, h.w, l.w);
            *(uint4*)(xbn + xwoff)         = h;
            *(uint4*)(xbn + XHALF + xwoff) = l;
        }
        // bar A: all W(c)/x(c) reads consumed + my x writes visible
        asm volatile("s_waitcnt lgkmcnt(0)" ::: "memory");
        __builtin_amdgcn_sched_barrier(0);
        __builtin_amdgcn_s_barrier();
        __builtin_amdgcn_sched_barrier(0);

        if (more) {
            // ---- stage W(c+1) into the (now fully-read) single buffer ----
            const char* gh = wimg_hi + (size_t)(c + 1) * 16384;
            const char* gl = wimg_lo + (size_t)(c + 1) * 16384;
            gload16(gh + tid * 16,        wdh);
            gload16(gh + 8192 + tid * 16, wdh2);
            gload16(gl + tid * 16,        wdh + WLO);
            gload16(gl + 8192 + tid * 16, wdh2 + WLO);
            // bar B: W(c+1) DMA complete
            asm volatile("s_waitcnt vmcnt(0)" ::: "memory");
            __builtin_amdgcn_sched_barrier(0);
            __builtin_amdgcn_s_barrier();
            __builtin_amdgcn_sched_barrier(0);
        }
    }

    // ---- epilogue: prob = sigmoid(beta*(logit+b)) -> u16 LDS [128][PSTR] ----
    unsigned short* prob = (unsigned short*)smem;
    {
        float bb[4], bt[4];
#pragma unroll
        for (int cf = 0; cf < 4; ++cf) {
            int col = wc * 64 + cf * 16 + col16;
            bb[cf] = (col < N_INNER) ? bv[col]   : 0.f;
            bt[cf] = (col < N_INNER) ? beta[col] : 0.f;
        }
#pragma unroll
        for (int rf = 0; rf < 4; ++rf)
#pragma unroll
            for (int cf = 0; cf < 4; ++cf) {
                int col = wc * 64 + cf * 16 + col16;
#pragma unroll
                for (int r = 0; r < 4; ++r) {
                    int row = wr * 64 + rf * 16 + hi4 * 4 + r;
                    float t = (acc[rf][cf][r] + bb[cf]) * bt[cf];
                    // s = 1/(1+e^-t); rcp err ~2^-22 << u16 quant step 2^-16
                    float s = __builtin_amdgcn_rcpf(1.f + __expf(-t));
                    float u = fminf(s * 65536.f + 0.5f, 65535.f);
                    prob[row * PSTR + col] = (unsigned short)(unsigned)u;
                }
            }
    }
    __syncthreads();                 // B0: prob visible

    // ---- tree expansion: 4 threads/row, 64 leaves each ----
    const int prow = tid >> 2;           // 0..127
    const int qq   = tid & 3;            // top-2 leaf bits
    const unsigned short* pb = prob + prow * PSTR;
    float P[64];
    {
        float p0 = (float)pb[0] * INV64K;             float f0 = (qq & 2) ? (1.f - p0) : p0;
        float p1 = (float)pb[1 + (qq >> 1)] * INV64K; float f1 = (qq & 1) ? (1.f - p1) : p1;
        P[0] = f0 * f1;
    }
    TREE_STAGE(2) TREE_STAGE(3) TREE_STAGE(4) TREE_STAGE(5) TREE_STAGE(6) TREE_STAGE(7)

    // p -> global (output 1): 64 contiguous floats per thread
    {
        float* po = out + OUT_HDR + (size_t)(row0 + prow) * N_LEAF + qq * 64;
#pragma unroll
        for (int m = 0; m < 16; ++m)
            *(float4*)(po + m * 4) = make_float4(P[4*m], P[4*m+1], P[4*m+2], P[4*m+3]);
    }
    __syncthreads();                 // B1: all prob reads done

    // ---- P hi-image overlaying prob: [kc 8][koct 4][row 128][16B] + qq*32 skew ----
#pragma unroll
    for (int kk = 0; kk < 2; ++kk)
#pragma unroll
        for (int g = 0; g < 4; ++g) {
            int b = kk * 32 + g * 8;
            uint4 h;
            h.x = packhi2(P[b+0], P[b+1]);
            h.y = packhi2(P[b+2], P[b+3]);
            h.z = packhi2(P[b+4], P[b+5]);
            h.w = packhi2(P[b+6], P[b+7]);
            *(uint4*)(smem + (2*qq + kk) * 8192 + g * 2048 + prow * 16 + qq * 32) = h;
        }
    __syncthreads();                 // B2: hi image visible

    // ---- out = p @ Q via MFMA; wave w owns rows w*16..w*16+15, cols 0..31 ----
    f32x4 acc2[2];
    acc2[0] = (f32x4){0.f,0.f,0.f,0.f};
    acc2[1] = (f32x4){0.f,0.f,0.f,0.f};
    const int arow = w * 16 + col16;

    // pass A: P_hi x (Q_hi + Q_lo)
#pragma unroll
    for (int kc = 0; kc < 8; ++kc) {
        bf16x8 pa = *(const bf16x8*)(smem + kc * 8192 + hi4 * 2048 + arow * 16 + (kc >> 1) * 32);
#pragma unroll
        for (int cf = 0; cf < 2; ++cf) {
            int qo = (cf * 16 + col16) * 256 + kc * 32 + hi4 * 8;
            bf16x8 qbh = *(const bf16x8*)(qhi + qo);
            bf16x8 qbl = *(const bf16x8*)(qlo + qo);
            acc2[cf] = MFMA_BF16(pa, qbh, acc2[cf]);
            acc2[cf] = MFMA_BF16(pa, qbl, acc2[cf]);
        }
    }
    __syncthreads();                 // B3: P_hi reads done

    // ---- P lo-image overwrite ----
#pragma unroll
    for (int kk = 0; kk < 2; ++kk)
#pragma unroll
        for (int g = 0; g < 4; ++g) {
            int b = kk * 32 + g * 8;
            uint4 l;
            l.x = packlo2(P[b+0], P[b+1]);
            l.y = packlo2(P[b+2], P[b+3]);
            l.z = packlo2(P[b+4], P[b+5]);
            l.w = packlo2(P[b+6], P[b+7]);
            *(uint4*)(smem + (2*qq + kk) * 8192 + g * 2048 + prow * 16 + qq * 32) = l;
        }
    __syncthreads();                 // B4

    // pass B: P_lo x Q_hi, then store out
#pragma unroll
    for (int kc = 0; kc < 8; ++kc) {
        bf16x8 pl = *(const bf16x8*)(smem + kc * 8192 + hi4 * 2048 + arow * 16 + (kc >> 1) * 32);
#pragma unroll
        for (int cf = 0; cf < 2; ++cf) {
            int qo = (cf * 16 + col16) * 256 + kc * 32 + hi4 * 8;
            bf16x8 qbh = *(const bf16x8*)(qhi + qo);
            acc2[cf] = MFMA_BF16(pl, qbh, acc2[cf]);
        }
    }
#pragma unroll
    for (int cf = 0; cf < 2; ++cf)
#pragma unroll
        for (int r = 0; r < 4; ++r) {
            int row = w * 16 + hi4 * 4 + r;
            out[(size_t)(row0 + row) * OUT_DIM + cf * 16 + col16] = acc2[cf][r];
        }
}

extern "C" void kernel_launch(void* const* d_in, const int* in_sizes, int n_in,
                              void* d_out, int out_size, void* d_ws, size_t ws_size,
                              hipStream_t stream) {
    const float* x    = (const float*)d_in[0];
    const float* W    = (const float*)d_in[1];
    const float* bv   = (const float*)d_in[2];
    const float* beta = (const float*)d_in[3];
    const float* leaf = (const float*)d_in[4];
    float* out = (float*)d_out;
    char* ws = (char*)d_ws;

    unsigned short* qhi = (unsigned short*)(ws + WS_QT_HI);
    unsigned short* qlo = (unsigned short*)(ws + WS_QT_LO);
    char* whi = ws + WS_WIMG_HI;
    char* wlo = ws + WS_WIMG_LO;

    hipFuncSetAttribute(reinterpret_cast<const void*>(tree_k),
                        hipFuncAttributeMaxDynamicSharedMemorySize, SMEM_BYTES);

    wsplit_k<<<16, 512, 0, stream>>>(W, (unsigned int*)whi, (unsigned int*)wlo);
    qt_k<<<1, 256, 0, stream>>>(leaf, qhi, qlo);
    tree_k<<<BATCH / TILE_M, NTHR, SMEM_BYTES, stream>>>(
        x, bv, beta, qhi, qlo, whi, wlo, out);
}